// Round 8
// baseline (611.746 us; speedup 1.0000x reference)
//
#include <hip/hip_runtime.h>
#include <math.h>

#define BB 32
#define NNODE 1024
#define BN 32768
#define NE 262144
#define DD 128
#define NT 8
#define NSTEPS 6

typedef __attribute__((ext_vector_type(8))) short bf16x8;
typedef __attribute__((ext_vector_type(4))) float f32x4;

static __device__ __forceinline__ float4 ld4(const float* p) { return *(const float4*)p; }
static __device__ __forceinline__ float sigmoidf_(float x) { return 1.f / (1.f + expf(-x)); }
// f32 -> bf16 round-to-nearest-even
static __device__ __forceinline__ unsigned f2b(float f) {
    unsigned u = __float_as_uint(f);
    return (u + 0x7FFFu + ((u >> 16) & 1u)) >> 16;
}
static __device__ __forceinline__ float b2f(unsigned short b) {
    return __uint_as_float(((unsigned)b) << 16);
}
static __device__ __forceinline__ unsigned pk(float a, float b) {
    return f2b(a) | (f2b(b) << 16);
}
// elementwise u16 max of packed pairs (valid ordering for non-negative bf16)
static __device__ __forceinline__ unsigned bmax2(unsigned a, unsigned b) {
    unsigned ah = a & 0xFFFF0000u, bh = b & 0xFFFF0000u;
    unsigned al = a & 0x0000FFFFu, bl = b & 0x0000FFFFu;
    return (ah > bh ? ah : bh) | (al > bl ? al : bl);
}
static __device__ __forceinline__ uint4 bmax4(uint4 a, uint4 b) {
    return make_uint4(bmax2(a.x, b.x), bmax2(a.y, b.y), bmax2(a.z, b.z), bmax2(a.w, b.w));
}

// ---------------- workspace layout (bytes) ----------------
static constexpr size_t OFF_HCUR = 0;                                   // BN*DD f32
static constexpr size_t OFF_HBF  = OFF_HCUR + (size_t)BN * DD * 4;      // BN*DD bf16
static constexpr size_t OFF_CNT  = OFF_HBF  + (size_t)BN * DD * 2;      // BN*NT i32
static constexpr size_t OFF_DOFF = OFF_CNT  + (size_t)BN * NT * 4;      // BN i32
static constexpr size_t OFF_DBLK = OFF_DOFF + (size_t)BN * 4;           // 512 B
static constexpr size_t OFF_VTOF = OFF_DBLK + 512;                      // BN*NT i32
static constexpr size_t OFF_VTCU = OFF_VTOF + (size_t)BN * NT * 4;      // BN*NT i32
static constexpr size_t OFF_SRC2 = OFF_VTCU + (size_t)BN * NT * 4;      // NE i32
static constexpr size_t OFF_WMB  = OFF_SRC2 + (size_t)NE * 4;           // 8*128*128 bf16
static constexpr size_t OFF_WIHB = OFF_WMB  + (size_t)NT * DD * DD * 2;
static constexpr size_t OFF_WHHB = OFF_WIHB + (size_t)3 * DD * DD * 2;
static constexpr size_t OFF_W1PY = OFF_WHHB + (size_t)3 * DD * DD * 2;  // 3*128*128 bf16
static constexpr size_t OFF_W1PZ = OFF_W1PY + (size_t)3 * 128 * 128 * 2;// 3*256*256 bf16
static constexpr size_t OFF_W2YB = OFF_W1PZ + (size_t)3 * 256 * 256 * 2;// 128*128 bf16
static constexpr size_t OFF_W2ZB = OFF_W2YB + (size_t)128 * 128 * 2;    // 256*256 bf16
static constexpr size_t OFF_ABF  = OFF_W2ZB + (size_t)256 * 256 * 2;    // BN*DD bf16
static constexpr size_t OFF_UN   = OFF_ABF  + (size_t)BN * DD * 2;      // conv scratch
static constexpr size_t OFF_U1Y  = OFF_UN;                                 // 32*1024*128 bf16
static constexpr size_t OFF_U1Z  = OFF_U1Y + (size_t)32 * 1024 * 128 * 2;  // 32*1024*256 bf16
static constexpr size_t OFF_QY   = OFF_U1Z + (size_t)32 * 1024 * 256 * 2;  // 32*255*128 f32
static constexpr size_t OFF_QZ   = OFF_QY  + (size_t)32 * 255 * 128 * 4;   // 32*255*256 f32
static constexpr size_t WS_NEED  = OFF_QZ  + (size_t)32 * 255 * 256 * 4;   // ~77 MiB

// ---------------- mega prep kernel ----------------
// [0,4096) hcur+hbf | [4096,4224) wmb | [4224,4272) wihb | [4272,4320) whhb
// [4320,4336) w2yb | [4336,4400) w2zb | [4400,4592) w1py | [4592,5360) w1pz | [5360,5616) cnt=0
#define PREP_BLOCKS 5616
__global__ void k_prep(const float* __restrict__ h_in, float* __restrict__ hcur,
                       unsigned short* __restrict__ hbf,
                       const float* __restrict__ Wmsg, unsigned short* __restrict__ wmb,
                       const float* __restrict__ wih, unsigned short* __restrict__ wihb,
                       const float* __restrict__ whh, unsigned short* __restrict__ whhb,
                       const float* __restrict__ c2w, unsigned short* __restrict__ w2yb,
                       const float* __restrict__ z2w, unsigned short* __restrict__ w2zb,
                       const float* __restrict__ c1w, unsigned short* __restrict__ w1py,
                       const float* __restrict__ z1w, unsigned short* __restrict__ w1pz,
                       int* __restrict__ cnt)
{
    int blk = blockIdx.x, tid = threadIdx.x;
    if (blk < 4096) {
        int i = blk * 256 + tid;
        float4 v = ((const float4*)h_in)[i];
        ((float4*)hcur)[i] = v;
        ((uint2*)hbf)[i] = make_uint2(pk(v.x, v.y), pk(v.z, v.w));
    } else if (blk < 4224) {
        int i = (blk - 4096) * 256 + tid;
        float4 v = ((const float4*)Wmsg)[i];
        ((uint2*)wmb)[i] = make_uint2(pk(v.x, v.y), pk(v.z, v.w));
    } else if (blk < 4272) {
        int i = (blk - 4224) * 256 + tid;
        float4 v = ((const float4*)wih)[i];
        ((uint2*)wihb)[i] = make_uint2(pk(v.x, v.y), pk(v.z, v.w));
    } else if (blk < 4320) {
        int i = (blk - 4272) * 256 + tid;
        float4 v = ((const float4*)whh)[i];
        ((uint2*)whhb)[i] = make_uint2(pk(v.x, v.y), pk(v.z, v.w));
    } else if (blk < 4336) {
        int i = (blk - 4320) * 256 + tid;
        float4 v = ((const float4*)c2w)[i];
        ((uint2*)w2yb)[i] = make_uint2(pk(v.x, v.y), pk(v.z, v.w));
    } else if (blk < 4400) {
        int i = (blk - 4336) * 256 + tid;
        float4 v = ((const float4*)z2w)[i];
        ((uint2*)w2zb)[i] = make_uint2(pk(v.x, v.y), pk(v.z, v.w));
    } else if (blk < 4592) {
        int g = (blk - 4400) * 256 + tid;          // < 3*128*128
        int k = g >> 14, rem = g & 16383;
        w1py[g] = (unsigned short)f2b(c1w[(size_t)rem * 3 + k]);
    } else if (blk < 5360) {
        int g = (blk - 4592) * 256 + tid;          // < 3*256*256
        int k = g >> 16, rem = g & 65535;
        w1pz[g] = (unsigned short)f2b(z1w[(size_t)rem * 3 + k]);
    } else {
        ((uint4*)cnt)[(blk - 5360) * 256 + tid] = make_uint4(0, 0, 0, 0);
    }
}

// ---------------- graph preprocessing: (dst,etype) CSR ----------------

__global__ void k_hist(const int* __restrict__ et, const int* __restrict__ dst,
                       int* __restrict__ cnt)
{
    int base = blockIdx.x * 1024, tid = threadIdx.x;
    for (int k = 0; k < 4; ++k) {
        int e = base + tid + k * 256;
        atomicAdd(&cnt[(size_t)dst[e] * NT + et[e]], 1);
    }
}

// per-node degree + block-local exclusive scan; dblk[blk] = block total
__global__ void k_degA(const int* __restrict__ cnt, int* __restrict__ doff,
                       int* __restrict__ dblk)
{
    __shared__ int ps[256];
    int tid = threadIdx.x;
    int v = blockIdx.x * 256 + tid;
    const int* cv = cnt + (size_t)v * NT;
    int d = 0;
#pragma unroll
    for (int t = 0; t < NT; ++t) d += cv[t];
    ps[tid] = d;
    __syncthreads();
    for (int off = 1; off < 256; off <<= 1) {
        int x = 0;
        if (tid >= off) x = ps[tid - off];
        __syncthreads();
        ps[tid] += x;
        __syncthreads();
    }
    doff[v] = ps[tid] - d;
    if (tid == 255) dblk[blockIdx.x] = ps[255];
}

__global__ void k_scan2(int* __restrict__ dblk)
{
    __shared__ int s[128];
    int tid = threadIdx.x;            // 128 threads
    s[tid] = dblk[tid];
    __syncthreads();
    if (tid == 0) {
        int run = 0;
        for (int i = 0; i < 128; ++i) { int x = s[i]; s[i] = run; run += x; }
    }
    __syncthreads();
    dblk[tid] = s[tid];
}

// vtoff[v][t] = global CSR offset for (v,t); vtcur = mutable copy for scatter
__global__ void k_degB(const int* __restrict__ cnt, const int* __restrict__ doff,
                       const int* __restrict__ dblk,
                       int* __restrict__ vtoff, int* __restrict__ vtcur)
{
    int v = blockIdx.x * 256 + threadIdx.x;
    int run = doff[v] + dblk[blockIdx.x];
    const int* cv = cnt + (size_t)v * NT;
    int* vo = vtoff + (size_t)v * NT;
    int* vc = vtcur + (size_t)v * NT;
#pragma unroll
    for (int t = 0; t < NT; ++t) { vo[t] = run; vc[t] = run; run += cv[t]; }
}

__global__ void k_scatter(const int* __restrict__ src, const int* __restrict__ dst,
                          const int* __restrict__ et,
                          int* __restrict__ vtcur, int* __restrict__ ssrc2)
{
    int e = blockIdx.x * 256 + threadIdx.x;
    int slot = atomicAdd(&vtcur[(size_t)dst[e] * NT + et[e]], 1);
    ssrc2[slot] = src[e];
}

// ---------------- fused message+aggregate: abf[v] = bf16(bias_seed + sum_t W_t . sum_e h[src]) ----------------
// 64-node tile; per etype: gather-sum A rows (f32), stage W_t, GEMM-accumulate.

__launch_bounds__(256, 3)
__global__ void k_msgagg(const int* __restrict__ ssrc2, const int* __restrict__ vtoff,
                         const int* __restrict__ cnt,
                         const unsigned short* __restrict__ hbf,
                         const unsigned short* __restrict__ wmb,
                         const float* __restrict__ bmsg,
                         unsigned short* __restrict__ abf)
{
    __shared__ __align__(16) unsigned short As[64 * 128];
    __shared__ __align__(16) unsigned short Ws[128 * 128];
    __shared__ float bm[NT * DD];
    int m0 = blockIdx.x * 64;
    int tid = threadIdx.x;
    *(float4*)&bm[tid * 4] = ld4(bmsg + tid * 4);   // 1024 f32
    int lane = tid & 63, wv = tid >> 6;
    int wm = (wv >> 1) * 32, wn = (wv & 1) * 64;
    int lr = lane & 15, lk = lane >> 4;
    f32x4 acc[2][4];
#pragma unroll
    for (int i = 0; i < 2; ++i)
#pragma unroll
        for (int j = 0; j < 4; ++j) acc[i][j] = (f32x4){0.f, 0.f, 0.f, 0.f};

    int rA = tid >> 2, qA = tid & 3;          // As: 64 rows x 4 quads of 32 cols
    unsigned bA = rA * 256 + qA * 64, swA = (rA & 7) << 4;
    int rW = tid >> 1, hW = tid & 1;          // Ws: 128 rows x 2 halves of 64 cols
    unsigned bW = rW * 256 + hW * 128, swW = (rW & 7) << 4;
    int node = m0 + rA;

#pragma unroll
    for (int t = 0; t < NT; ++t) {
        __syncthreads();                      // WAR vs previous MFMA reads (covers bm store at t=0)
        {
            int start = vtoff[(size_t)node * NT + t];
            int cv    = cnt[(size_t)node * NT + t];
            if (cv == 1) {
                const uint4* sp = (const uint4*)(hbf + (size_t)ssrc2[start] * DD + qA * 32);
#pragma unroll
                for (int c = 0; c < 4; ++c)
                    *(uint4*)((char*)As + ((bA + c * 16) ^ swA)) = sp[c];
            } else if (cv == 0) {
                uint4 z = make_uint4(0, 0, 0, 0);
#pragma unroll
                for (int c = 0; c < 4; ++c)
                    *(uint4*)((char*)As + ((bA + c * 16) ^ swA)) = z;
            } else {
                float ac[32];
#pragma unroll
                for (int j = 0; j < 32; ++j) ac[j] = 0.f;
                for (int i = 0; i < cv; ++i) {
                    const uint4* sp = (const uint4*)(hbf + (size_t)ssrc2[start + i] * DD + qA * 32);
#pragma unroll
                    for (int c = 0; c < 4; ++c) {
                        uint4 w = sp[c];
                        ac[c * 8 + 0] += b2f((unsigned short)(w.x & 0xFFFF));
                        ac[c * 8 + 1] += b2f((unsigned short)(w.x >> 16));
                        ac[c * 8 + 2] += b2f((unsigned short)(w.y & 0xFFFF));
                        ac[c * 8 + 3] += b2f((unsigned short)(w.y >> 16));
                        ac[c * 8 + 4] += b2f((unsigned short)(w.z & 0xFFFF));
                        ac[c * 8 + 5] += b2f((unsigned short)(w.z >> 16));
                        ac[c * 8 + 6] += b2f((unsigned short)(w.w & 0xFFFF));
                        ac[c * 8 + 7] += b2f((unsigned short)(w.w >> 16));
                    }
                }
#pragma unroll
                for (int c = 0; c < 4; ++c) {
                    uint4 o = make_uint4(pk(ac[c * 8 + 0], ac[c * 8 + 1]), pk(ac[c * 8 + 2], ac[c * 8 + 3]),
                                         pk(ac[c * 8 + 4], ac[c * 8 + 5]), pk(ac[c * 8 + 6], ac[c * 8 + 7]));
                    *(uint4*)((char*)As + ((bA + c * 16) ^ swA)) = o;
                }
            }
        }
        {
            const uint4* wp = (const uint4*)(wmb + ((size_t)t * DD + rW) * DD + hW * 64);
#pragma unroll
            for (int c = 0; c < 8; ++c)
                *(uint4*)((char*)Ws + ((bW + c * 16) ^ swW)) = wp[c];
        }
        __syncthreads();
#pragma unroll
        for (int kc = 0; kc < 4; ++kc) {
            int cb = kc * 64 + lk * 16;
            bf16x8 af[2], bfv[4];
#pragma unroll
            for (int mi = 0; mi < 2; ++mi) {
                int row = wm + mi * 16 + lr;
                af[mi] = *(const bf16x8*)((const char*)As + ((row * 256 + cb) ^ ((row & 7) << 4)));
            }
#pragma unroll
            for (int ni = 0; ni < 4; ++ni) {
                int row = wn + ni * 16 + lr;
                bfv[ni] = *(const bf16x8*)((const char*)Ws + ((row * 256 + cb) ^ ((row & 7) << 4)));
            }
#pragma unroll
            for (int mi = 0; mi < 2; ++mi)
#pragma unroll
                for (int ni = 0; ni < 4; ++ni)
                    acc[mi][ni] = __builtin_amdgcn_mfma_f32_16x16x32_bf16(af[mi], bfv[ni], acc[mi][ni], 0, 0, 0);
        }
    }
    // epilogue: + bias_seed, write abf
#pragma unroll
    for (int mi = 0; mi < 2; ++mi)
#pragma unroll
        for (int rg = 0; rg < 4; ++rg) {
            int v = m0 + wm + mi * 16 + lk * 4 + rg;
            const int* cvp = cnt + (size_t)v * NT;
            float c0 = (float)cvp[0], c1 = (float)cvp[1], c2 = (float)cvp[2], c3 = (float)cvp[3];
            float c4 = (float)cvp[4], c5 = (float)cvp[5], c6 = (float)cvp[6], c7 = (float)cvp[7];
#pragma unroll
            for (int ni = 0; ni < 4; ++ni) {
                int col = wn + ni * 16 + lr;
                float bias = c0 * bm[col] + c1 * bm[DD + col] + c2 * bm[2 * DD + col] + c3 * bm[3 * DD + col]
                           + c4 * bm[4 * DD + col] + c5 * bm[5 * DD + col] + c6 * bm[6 * DD + col] + c7 * bm[7 * DD + col];
                abf[(size_t)v * DD + col] = (unsigned short)f2b(acc[mi][ni][rg] + bias);
            }
        }
}

// ---------------- merged MFMA GRU: M=128 tile, 512 threads, all gates in-register ----------------

__launch_bounds__(512, 2)
__global__ void k_gru(const unsigned short* __restrict__ abf, float* __restrict__ h,
                      unsigned short* __restrict__ hbf,
                      const unsigned short* __restrict__ wihb, const unsigned short* __restrict__ whhb,
                      const float* __restrict__ bih, const float* __restrict__ bhh)
{
    __shared__ __align__(16) unsigned short Xs[128 * 128];
    __shared__ __align__(16) unsigned short Ws2[128 * 128];
    int m0 = blockIdx.x * 128;
    int tid = threadIdx.x;
    int lane = tid & 63, wv = tid >> 6;      // 8 waves
    int wm = (wv >> 1) * 32, wn = (wv & 1) * 64;
    int lr = lane & 15, lk = lane >> 4;
    f32x4 aR[2][4], aZ[2][4], aI[2][4], aH[2][4];
#pragma unroll
    for (int i = 0; i < 2; ++i)
#pragma unroll
        for (int j = 0; j < 4; ++j) {
            aR[i][j] = (f32x4){0.f, 0.f, 0.f, 0.f};
            aZ[i][j] = (f32x4){0.f, 0.f, 0.f, 0.f};
            aI[i][j] = (f32x4){0.f, 0.f, 0.f, 0.f};
            aH[i][j] = (f32x4){0.f, 0.f, 0.f, 0.f};
        }
    int rx = tid >> 2, qx = tid & 3;         // 128 rows x 4 quads (512 threads)
    unsigned bx = rx * 256 + qx * 64, swx = (rx & 7) << 4;
#pragma unroll
    for (int pass = 0; pass < 2; ++pass) {
        const unsigned short* X = pass ? hbf : abf;
        const unsigned short* W = pass ? whhb : wihb;
#pragma unroll
        for (int g = 0; g < 3; ++g) {
            __syncthreads();                 // WAR: prior reads of Xs/Ws2 done
            if (g == 0) {
                const uint4* sp = (const uint4*)(X + (size_t)(m0 + rx) * DD + qx * 32);
#pragma unroll
                for (int c = 0; c < 4; ++c)
                    *(uint4*)((char*)Xs + ((bx + c * 16) ^ swx)) = sp[c];
            }
            {
                const uint4* wp = (const uint4*)(W + (size_t)(g * DD + rx) * DD + qx * 32);
#pragma unroll
                for (int c = 0; c < 4; ++c)
                    *(uint4*)((char*)Ws2 + ((bx + c * 16) ^ swx)) = wp[c];
            }
            __syncthreads();
#pragma unroll
            for (int kc = 0; kc < 4; ++kc) {
                int cb = kc * 64 + lk * 16;
                bf16x8 af[2], bfv[4];
#pragma unroll
                for (int mi = 0; mi < 2; ++mi) {
                    int row = wm + mi * 16 + lr;
                    af[mi] = *(const bf16x8*)((const char*)Xs + ((row * 256 + cb) ^ ((row & 7) << 4)));
                }
#pragma unroll
                for (int ni = 0; ni < 4; ++ni) {
                    int row = wn + ni * 16 + lr;
                    bfv[ni] = *(const bf16x8*)((const char*)Ws2 + ((row * 256 + cb) ^ ((row & 7) << 4)));
                }
#pragma unroll
                for (int mi = 0; mi < 2; ++mi)
#pragma unroll
                    for (int ni = 0; ni < 4; ++ni) {
                        if (g == 0)
                            aR[mi][ni] = __builtin_amdgcn_mfma_f32_16x16x32_bf16(af[mi], bfv[ni], aR[mi][ni], 0, 0, 0);
                        else if (g == 1)
                            aZ[mi][ni] = __builtin_amdgcn_mfma_f32_16x16x32_bf16(af[mi], bfv[ni], aZ[mi][ni], 0, 0, 0);
                        else if (pass == 0)
                            aI[mi][ni] = __builtin_amdgcn_mfma_f32_16x16x32_bf16(af[mi], bfv[ni], aI[mi][ni], 0, 0, 0);
                        else
                            aH[mi][ni] = __builtin_amdgcn_mfma_f32_16x16x32_bf16(af[mi], bfv[ni], aH[mi][ni], 0, 0, 0);
                    }
            }
        }
    }
    // epilogue: full GRU combine in-register
#pragma unroll
    for (int ni = 0; ni < 4; ++ni) {
        int col = wn + ni * 16 + lr;
        float br_ = bih[col] + bhh[col];
        float bz_ = bih[DD + col] + bhh[DD + col];
        float bin_ = bih[2 * DD + col], bhn_ = bhh[2 * DD + col];
#pragma unroll
        for (int mi = 0; mi < 2; ++mi)
#pragma unroll
            for (int rg = 0; rg < 4; ++rg) {
                int v = m0 + wm + mi * 16 + lk * 4 + rg;
                float rr = sigmoidf_(aR[mi][ni][rg] + br_);
                float zz = sigmoidf_(aZ[mi][ni][rg] + bz_);
                float nn = tanhf(aI[mi][ni][rg] + bin_ + rr * (aH[mi][ni][rg] + bhn_));
                float hold = h[(size_t)v * DD + col];
                float hnew = (1.f - zz) * nn + zz * hold;
                h[(size_t)v * DD + col] = hnew;
                hbf[(size_t)v * DD + col] = (unsigned short)f2b(hnew);
            }
    }
}

// ---------------- MFMA conv1(k=3): U1[b][pos][co] = relu(conv+b), unpooled, bf16 ----------------

template <int CIN>
__launch_bounds__(256, 2)
__global__ void k_conv1m(const unsigned short* __restrict__ hbf, const float* __restrict__ h0,
                         const unsigned short* __restrict__ w1p, const float* __restrict__ bias,
                         unsigned short* __restrict__ U1)
{
    __shared__ __align__(16) unsigned short As[128 * 64];
    __shared__ __align__(16) unsigned short Ws[128 * 64];
    int p0 = blockIdx.x * 128, b = blockIdx.y, n0 = blockIdx.z * 128;
    int tid = threadIdx.x;
    int lane = tid & 63, wv = tid >> 6;
    int wm = (wv >> 1) * 64, wn = (wv & 1) * 64;
    int lr = lane & 15, lk = lane >> 4;
    f32x4 acc[4][4];
#pragma unroll
    for (int i = 0; i < 4; ++i)
#pragma unroll
        for (int j = 0; j < 4; ++j) acc[i][j] = (f32x4){0.f, 0.f, 0.f, 0.f};

    int r = tid >> 1, halfc = tid & 1;
    unsigned boff = r * 128 + halfc * 64;
    unsigned sw = (r & 7) << 4;
#pragma unroll
    for (int k = 0; k < 3; ++k) {
        for (int c0 = 0; c0 < CIN; c0 += 64) {
            __syncthreads();
            {
                int row = p0 + k + r; if (row > NNODE - 1) row = NNODE - 1;
                int ci = c0 + halfc * 32;
                if (CIN == 128 || ci < 128) {
                    const uint4* sp = (const uint4*)(hbf + ((size_t)(b * NNODE + row)) * DD + ci);
#pragma unroll
                    for (int c = 0; c < 4; ++c)
                        *(uint4*)((char*)As + ((boff + c * 16) ^ sw)) = sp[c];
                } else {
                    const float4* sp = (const float4*)(h0 + ((size_t)(b * NNODE + row)) * DD + (ci - 128));
#pragma unroll
                    for (int c = 0; c < 4; ++c) {
                        float4 v0 = sp[2 * c], v1 = sp[2 * c + 1];
                        *(uint4*)((char*)As + ((boff + c * 16) ^ sw)) =
                            make_uint4(pk(v0.x, v0.y), pk(v0.z, v0.w), pk(v1.x, v1.y), pk(v1.z, v1.w));
                    }
                }
            }
            {
                const uint4* wp = (const uint4*)(w1p + ((size_t)k * CIN + n0 + r) * CIN + c0 + halfc * 32);
#pragma unroll
                for (int c = 0; c < 4; ++c)
                    *(uint4*)((char*)Ws + ((boff + c * 16) ^ sw)) = wp[c];
            }
            __syncthreads();
#pragma unroll
            for (int kc = 0; kc < 2; ++kc) {
                int cb = kc * 64 + lk * 16;
                bf16x8 af[4], bfv[4];
#pragma unroll
                for (int mi = 0; mi < 4; ++mi) {
                    int row = wm + mi * 16 + lr;
                    af[mi] = *(const bf16x8*)((const char*)As + ((row * 128 + cb) ^ ((row & 7) << 4)));
                }
#pragma unroll
                for (int ni = 0; ni < 4; ++ni) {
                    int row = wn + ni * 16 + lr;
                    bfv[ni] = *(const bf16x8*)((const char*)Ws + ((row * 128 + cb) ^ ((row & 7) << 4)));
                }
#pragma unroll
                for (int mi = 0; mi < 4; ++mi)
#pragma unroll
                    for (int ni = 0; ni < 4; ++ni)
                        acc[mi][ni] = __builtin_amdgcn_mfma_f32_16x16x32_bf16(af[mi], bfv[ni], acc[mi][ni], 0, 0, 0);
            }
        }
    }
#pragma unroll
    for (int ni = 0; ni < 4; ++ni) {
        int co = n0 + wn + ni * 16 + lr;
        float bs = bias[co];
#pragma unroll
        for (int mi = 0; mi < 4; ++mi)
#pragma unroll
            for (int rg = 0; rg < 4; ++rg) {
                int pos = p0 + wm + mi * 16 + lk * 4 + rg;
                if (pos < NNODE - 2) {
                    float v = fmaxf(0.f, acc[mi][ni][rg] + bs);
                    U1[((size_t)b * NNODE + pos) * CIN + co] = (unsigned short)f2b(v);
                }
            }
    }
}

// ---------------- MFMA conv2(k=1): A = pool3(U1) on the fly; epilogue pool2 ----------------

template <int CIN>
__launch_bounds__(256, 2)
__global__ void k_conv2m(const unsigned short* __restrict__ U1, const unsigned short* __restrict__ w2b,
                         const float* __restrict__ bias, float* __restrict__ Q)
{
    __shared__ __align__(16) unsigned short As[128 * 64];
    __shared__ __align__(16) unsigned short Ws[128 * 64];
    int m0 = blockIdx.x * 128, b = blockIdx.y, n0 = blockIdx.z * 128;
    int tid = threadIdx.x;
    int lane = tid & 63, wv = tid >> 6;
    int wm = (wv >> 1) * 64, wn = (wv & 1) * 64;
    int lr = lane & 15, lk = lane >> 4;
    f32x4 acc[4][4];
#pragma unroll
    for (int i = 0; i < 4; ++i)
#pragma unroll
        for (int j = 0; j < 4; ++j) acc[i][j] = (f32x4){0.f, 0.f, 0.f, 0.f};

    int r = tid >> 1, halfc = tid & 1;
    unsigned boff = r * 128 + halfc * 64;
    unsigned sw = (r & 7) << 4;
    for (int c0 = 0; c0 < CIN; c0 += 64) {
        __syncthreads();
        {
            int pr = 2 * (m0 + r);
            int r0 = pr, r1 = pr + 1, r2v = pr + 2;
            if (r2v > NNODE - 1) r2v = NNODE - 1;
            if (r1 > NNODE - 1) r1 = NNODE - 1;
            int ci = c0 + halfc * 32;
            const unsigned short* bp = U1 + (size_t)b * NNODE * CIN + ci;
            const uint4* p0q = (const uint4*)(bp + (size_t)r0 * CIN);
            const uint4* p1q = (const uint4*)(bp + (size_t)r1 * CIN);
            const uint4* p2q = (const uint4*)(bp + (size_t)r2v * CIN);
#pragma unroll
            for (int c = 0; c < 4; ++c) {
                uint4 mm = bmax4(bmax4(p0q[c], p1q[c]), p2q[c]);
                *(uint4*)((char*)As + ((boff + c * 16) ^ sw)) = mm;
            }
        }
        {
            const uint4* wp = (const uint4*)(w2b + (size_t)(n0 + r) * CIN + c0 + halfc * 32);
#pragma unroll
            for (int c = 0; c < 4; ++c)
                *(uint4*)((char*)Ws + ((boff + c * 16) ^ sw)) = wp[c];
        }
        __syncthreads();
#pragma unroll
        for (int kc = 0; kc < 2; ++kc) {
            int cb = kc * 64 + lk * 16;
            bf16x8 af[4], bfv[4];
#pragma unroll
            for (int mi = 0; mi < 4; ++mi) {
                int row = wm + mi * 16 + lr;
                af[mi] = *(const bf16x8*)((const char*)As + ((row * 128 + cb) ^ ((row & 7) << 4)));
            }
#pragma unroll
            for (int ni = 0; ni < 4; ++ni) {
                int row = wn + ni * 16 + lr;
                bfv[ni] = *(const bf16x8*)((const char*)Ws + ((row * 128 + cb) ^ ((row & 7) << 4)));
            }
#pragma unroll
            for (int mi = 0; mi < 4; ++mi)
#pragma unroll
                for (int ni = 0; ni < 4; ++ni)
                    acc[mi][ni] = __builtin_amdgcn_mfma_f32_16x16x32_bf16(af[mi], bfv[ni], acc[mi][ni], 0, 0, 0);
        }
    }
#pragma unroll
    for (int ni = 0; ni < 4; ++ni) {
        int co = n0 + wn + ni * 16 + lr;
        float bs = bias[co];
#pragma unroll
        for (int mi = 0; mi < 4; ++mi) {
            int l0 = m0 + wm + mi * 16 + lk * 4;
            float v0 = fmaxf(0.f, acc[mi][ni][0] + bs);
            float v1 = fmaxf(0.f, acc[mi][ni][1] + bs);
            float v2 = fmaxf(0.f, acc[mi][ni][2] + bs);
            float v3 = fmaxf(0.f, acc[mi][ni][3] + bs);
            int jq = l0 >> 1;
            if (jq < 255)     Q[((size_t)b * 255 + jq) * CIN + co]     = fmaxf(v0, v1);
            if (jq + 1 < 255) Q[((size_t)b * 255 + jq + 1) * CIN + co] = fmaxf(v2, v3);
        }
    }
}

// ---------------- final reduction ----------------

__launch_bounds__(256)
__global__ void k_final(const float* __restrict__ QY, const float* __restrict__ QZ,
                        const float* __restrict__ wy, const float* __restrict__ by,
                        const float* __restrict__ wz, const float* __restrict__ bz,
                        float* __restrict__ out)
{
    int b = blockIdx.x, tid = threadIdx.x;
    float p = 0.f;
    if (tid < 255) {
        const float* qy = QY + ((size_t)(b * 255 + tid)) * 128;
        const float* qz = QZ + ((size_t)(b * 255 + tid)) * 256;
        float dy = 0.f, dz = 0.f;
        for (int c = 0; c < 128; c += 4) {
            float4 q = ld4(qy + c), wv = ld4(wy + c);
            dy += q.x * wv.x + q.y * wv.y + q.z * wv.z + q.w * wv.w;
        }
        for (int c = 0; c < 256; c += 4) {
            float4 q = ld4(qz + c), wv = ld4(wz + c);
            dz += q.x * wv.x + q.y * wv.y + q.z * wv.z + q.w * wv.w;
        }
        p = (dy + by[0]) * (dz + bz[0]);
    }
    __shared__ float red[4];
    for (int off = 32; off > 0; off >>= 1) p += __shfl_down(p, off);
    if ((tid & 63) == 0) red[tid >> 6] = p;
    __syncthreads();
    if (tid == 0) {
        float s = red[0] + red[1] + red[2] + red[3];
        out[b] = 1.f / (1.f + expf(-s / 255.f));
    }
}

// ---------------- launch ----------------

extern "C" void kernel_launch(void* const* d_in, const int* in_sizes, int n_in,
                              void* d_out, int out_size, void* d_ws, size_t ws_size,
                              hipStream_t stream)
{
    const float* h_in = (const float*)d_in[0];
    const int* src = (const int*)d_in[1];
    const int* dst = (const int*)d_in[2];
    const int* et  = (const int*)d_in[3];
    const float* Wmsg = (const float*)d_in[4];
    const float* bmsg = (const float*)d_in[5];
    const float* wih = (const float*)d_in[6];
    const float* whh = (const float*)d_in[7];
    const float* bih = (const float*)d_in[8];
    const float* bhh = (const float*)d_in[9];
    const float* c1w = (const float*)d_in[10];
    const float* c1b = (const float*)d_in[11];
    const float* c2w = (const float*)d_in[12];
    const float* c2b = (const float*)d_in[13];
    const float* z1w = (const float*)d_in[14];
    const float* z1b = (const float*)d_in[15];
    const float* z2w = (const float*)d_in[16];
    const float* z2b = (const float*)d_in[17];
    const float* wy  = (const float*)d_in[18];
    const float* by  = (const float*)d_in[19];
    const float* wz  = (const float*)d_in[20];
    const float* bz  = (const float*)d_in[21];
    float* out = (float*)d_out;

    if (ws_size < WS_NEED) return;   // loud failure: output stays poisoned

    char* ws = (char*)d_ws;
    float* hcur = (float*)(ws + OFF_HCUR);
    unsigned short* hbf  = (unsigned short*)(ws + OFF_HBF);
    int*   cnt   = (int*)(ws + OFF_CNT);
    int*   doff  = (int*)(ws + OFF_DOFF);
    int*   dblk  = (int*)(ws + OFF_DBLK);
    int*   vtoff = (int*)(ws + OFF_VTOF);
    int*   vtcur = (int*)(ws + OFF_VTCU);
    int*   ssrc2 = (int*)(ws + OFF_SRC2);
    unsigned short* wmb  = (unsigned short*)(ws + OFF_WMB);
    unsigned short* wihb = (unsigned short*)(ws + OFF_WIHB);
    unsigned short* whhb = (unsigned short*)(ws + OFF_WHHB);
    unsigned short* w1py = (unsigned short*)(ws + OFF_W1PY);
    unsigned short* w1pz = (unsigned short*)(ws + OFF_W1PZ);
    unsigned short* w2yb = (unsigned short*)(ws + OFF_W2YB);
    unsigned short* w2zb = (unsigned short*)(ws + OFF_W2ZB);
    unsigned short* abf  = (unsigned short*)(ws + OFF_ABF);
    unsigned short* U1Y  = (unsigned short*)(ws + OFF_U1Y);
    unsigned short* U1Z  = (unsigned short*)(ws + OFF_U1Z);
    float* QY   = (float*)(ws + OFF_QY);
    float* QZ   = (float*)(ws + OFF_QZ);

    k_prep<<<PREP_BLOCKS, 256, 0, stream>>>(h_in, hcur, hbf, Wmsg, wmb, wih, wihb, whh, whhb,
                                            c2w, w2yb, z2w, w2zb, c1w, w1py, z1w, w1pz, cnt);

    k_hist<<<256, 256, 0, stream>>>(et, dst, cnt);
    k_degA<<<128, 256, 0, stream>>>(cnt, doff, dblk);
    k_scan2<<<1, 128, 0, stream>>>(dblk);
    k_degB<<<128, 256, 0, stream>>>(cnt, doff, dblk, vtoff, vtcur);
    k_scatter<<<1024, 256, 0, stream>>>(src, dst, et, vtcur, ssrc2);

    for (int s = 0; s < NSTEPS; ++s) {
        k_msgagg<<<BN / 64, 256, 0, stream>>>(ssrc2, vtoff, cnt, hbf, wmb, bmsg, abf);
        k_gru<<<BN / 128, 512, 0, stream>>>(abf, hcur, hbf, wihb, whhb, bih, bhh);
    }

    k_conv1m<128><<<dim3(8, 32, 1), 256, 0, stream>>>(hbf, h_in, w1py, c1b, U1Y);
    k_conv2m<128><<<dim3(4, 32, 1), 256, 0, stream>>>(U1Y, w2yb, c2b, QY);
    k_conv1m<256><<<dim3(8, 32, 2), 256, 0, stream>>>(hbf, h_in, w1pz, z1b, U1Z);
    k_conv2m<256><<<dim3(4, 32, 2), 256, 0, stream>>>(U1Z, w2zb, z2b, QZ);
    k_final<<<32, 256, 0, stream>>>(QY, QZ, wy, by, wz, bz, out);
}